// Round 4
// baseline (123.256 us; speedup 1.0000x reference)
//
#include <hip/hip_runtime.h>

typedef __attribute__((ext_vector_type(8))) short bf16x8;
typedef __attribute__((ext_vector_type(16))) float f32x16;
typedef __attribute__((ext_vector_type(4))) float f32x4;
typedef __attribute__((ext_vector_type(4))) unsigned int u32x4;

#define NH 8
#define CD 64
#define TLEN 1024
#define SENC 1024
#define STOT 2048
#define NGRP 4                   // in-block key-split groups (2 waves each)
#define KRANGE (STOT / NGRP)     // 512 keys per group
#define SKG 32                   // keys per iter per group
#define NITG (KRANGE / SKG)      // 16 iters
#define BQ 64                    // queries per block (2 q-columns x 32)
#define QSCALE 0.18033688f   // 0.125 * log2(e); fixed-scale softmax: uniform
                             // scale on P cancels in (P.V)/sum(P) -> no max,
                             // and split partials combine by simple addition.

__device__ __forceinline__ ushort f2bf(float f) {
  uint x = __builtin_bit_cast(uint, f);
  uint r = (x + 0x7fffu + ((x >> 16) & 1u)) >> 16;
  return (ushort)r;
}
__device__ __forceinline__ uint4 pack8(const ushort* p) {
  uint4 u;
  u.x = (uint)p[0] | ((uint)p[1] << 16);
  u.y = (uint)p[2] | ((uint)p[3] << 16);
  u.z = (uint)p[4] | ((uint)p[5] << 16);
  u.w = (uint)p[6] | ((uint)p[7] << 16);
  return u;
}
// hw packed f32->bf16 (RNE)
__device__ __forceinline__ uint cvtpk(float lo, float hi) {
  uint r;
  asm("v_cvt_pk_bf16_f32 %0, %1, %2" : "=v"(r) : "v"(lo), "v"(hi));
  return r;
}
// exchange a.hi32lanes <-> b.lo32lanes (CDNA4 v_permlane32_swap_b32)
__device__ __forceinline__ void plswap(uint& a, uint& b) {
  asm("v_permlane32_swap_b32 %0, %1" : "+v"(a), "+v"(b));
}
__device__ __forceinline__ bf16x8 mk8(uint a, uint b, uint c, uint d) {
  u32x4 t = {a, b, c, d};
  return __builtin_bit_cast(bf16x8, t);
}

// ---------------- pre-pass: cast K/V to bf16 in workspace (unchanged) --------
// z=0: Kt[bh][key][ci] (transposed via fp32 LDS tile), z=1: Vn[bh][ci][key]
__global__ __launch_bounds__(256)
void repack_kernel(const float* __restrict__ x, const float* __restrict__ ekv,
                   ushort* __restrict__ ktw, ushort* __restrict__ vnw) {
  const int kx = blockIdx.x;   // key tile 0..31 (64 keys each)
  const int bh = blockIdx.y;   // 0..31
  const int b = bh >> 3, h = bh & 7;
  const int t = threadIdx.x;
  const float* ks;
  const float* vs;
  if (kx < 16) {
    ks = ekv + (size_t)(b * 2 * NH * CD + h * CD) * SENC + kx * 64;
    vs = ekv + (size_t)(b * 2 * NH * CD + NH * CD + h * CD) * SENC + kx * 64;
  } else {
    ks = x + (size_t)(b * 3 * NH * CD + NH * CD + h * CD) * TLEN + (kx - 16) * 64;
    vs = x + (size_t)(b * 3 * NH * CD + 2 * NH * CD + h * CD) * TLEN + (kx - 16) * 64;
  }
  if (blockIdx.z == 0) {
    __shared__ float Lt[64 * 65];
    const int ci = t >> 2, seg = t & 3;
#pragma unroll
    for (int j = 0; j < 4; ++j) {
      float4 d = *(const float4*)&ks[ci * 1024 + seg * 16 + 4 * j];
      Lt[ci * 65 + seg * 16 + 4 * j + 0] = d.x;
      Lt[ci * 65 + seg * 16 + 4 * j + 1] = d.y;
      Lt[ci * 65 + seg * 16 + 4 * j + 2] = d.z;
      Lt[ci * 65 + seg * 16 + 4 * j + 3] = d.w;
    }
    __syncthreads();
    const int key = t >> 2;
    ushort tmp[16];
#pragma unroll
    for (int u = 0; u < 16; ++u)
      tmp[u] = f2bf(Lt[(seg * 16 + u) * 65 + key]);
    ushort* dst = ktw + ((size_t)bh * STOT + kx * 64 + key) * CD + seg * 16;
    *(uint4*)dst = pack8(tmp);
    *(uint4*)(dst + 8) = pack8(tmp + 8);
  } else {
    const int ci = t >> 2, seg = t & 3;
    ushort tmp[16];
#pragma unroll
    for (int j = 0; j < 4; ++j) {
      float4 d = *(const float4*)&vs[ci * 1024 + seg * 16 + 4 * j];
      tmp[4 * j + 0] = f2bf(d.x);
      tmp[4 * j + 1] = f2bf(d.y);
      tmp[4 * j + 2] = f2bf(d.z);
      tmp[4 * j + 3] = f2bf(d.w);
    }
    ushort* dst = vnw + (size_t)bh * CD * STOT + (size_t)ci * STOT + kx * 64 + seg * 16;
    *(uint4*)dst = pack8(tmp);
    *(uint4*)(dst + 8) = pack8(tmp + 8);
  }
}

// ---------------- main flash kernel: in-block split-K-4, register P ----------
// 512 blocks x 8 waves (512 thr): wave w -> q-column (w&1), key-group (w>>1).
// Each group: 512 keys, SKG=32 per iter, own double-buffered LDS quarter.
// 2 blocks/CU -> 16 waves/CU = 4/SIMD. Partial-O merge in LDS; no combine
// kernel, no global partial traffic.
__global__ __launch_bounds__(512, 4)
void qkv_attn_ws(const float* __restrict__ x, const ushort* __restrict__ ktw,
                 const ushort* __restrict__ vnw, float* __restrict__ out) {
  // 64KB arena: [grp][buf][0=K(32x64),1=V(64x32)] 4KB each; epilogue reuses it
  __shared__ __align__(16) ushort arena[NGRP * 2 * 2 * SKG * CD];

  const int tid  = threadIdx.x;
  const int w    = tid >> 6;        // wave 0..7
  const int qcol = w & 1;           // q column (0/1)
  const int grp  = w >> 1;          // key-split group 0..3
  const int lane = tid & 63;
  const int al   = lane & 31;       // m/n index within 32-wide MFMA tile
  const int h    = lane >> 5;       // k-half selector
  const int tg   = tid & 127;       // thread index within group

  // XCD swizzle: all 16 q-tiles of one bh land on one XCD (id = f%8)
  // bits: [2:0]=bh_lo, [6:3]=qt, [8:7]=bh_hi  (bijective on 0..511)
  const int f  = blockIdx.x;
  const int bh = (f & 7) | (((f >> 7) & 3) << 3);
  const int qt = (f >> 3) & 15;
  const int b  = bh >> 3;
  const int hh = bh & 7;
  const int t0 = qt * BQ;
  const int kbase = grp * KRANGE;

  const float* qg = x + (size_t)(b * 3 * NH * CD + hh * CD) * TLEN;
  float* og = out + (size_t)(b * NH * CD + hh * CD) * TLEN;
  const ushort* ktb = ktw + (size_t)bh * STOT * CD;   // [key][ci]
  const ushort* vnb = vnw + (size_t)bh * CD * STOT;   // [ci][key]

  // group LDS slices
  ushort* Kg[2]; ushort* Vg[2];
#pragma unroll
  for (int buf = 0; buf < 2; ++buf) {
    Kg[buf] = arena + (size_t)((grp * 2 + buf) * 2 + 0) * (SKG * CD);
    Vg[buf] = arena + (size_t)((grp * 2 + buf) * 2 + 1) * (SKG * CD);
  }

  // ---- staging geometry (per group, 128 threads)
  // K tile [32 keys][64 ci] rows of 128B=8 chunks, chunk ^= (row&7)
  const int krow = tg >> 2;              // 0..31
  const int kcb  = (tg & 3) * 2;         // chunk base 0,2,4,6
  const int kswz0 = ((kcb + 0) ^ (krow & 7)) * 8;
  const int kswz1 = ((kcb + 1) ^ (krow & 7)) * 8;
  // V tile [64 ci][32 keys] rows of 64B=4 chunks, chunk ^= ((row>>1)&3)
  const int vrow = tg >> 1;              // 0..63
  const int vcb  = (tg & 1) * 2;         // chunk base 0,2
  const int vswz0 = ((vcb + 0) ^ ((vrow >> 1) & 3)) * 8;
  const int vswz1 = ((vcb + 1) ^ ((vrow >> 1) & 3)) * 8;

  // ---- prologue: load chunk 0 into regs, store swizzled into buf 0
  uint4 kp0 = *(const uint4*)(ktb + (size_t)(kbase + krow) * CD + (kcb + 0) * 8);
  uint4 kp1 = *(const uint4*)(ktb + (size_t)(kbase + krow) * CD + (kcb + 1) * 8);
  uint4 vp0 = *(const uint4*)(vnb + (size_t)vrow * STOT + kbase + (vcb + 0) * 8);
  uint4 vp1 = *(const uint4*)(vnb + (size_t)vrow * STOT + kbase + (vcb + 1) * 8);
  *(uint4*)&Kg[0][krow * CD + kswz0] = kp0;
  *(uint4*)&Kg[0][krow * CD + kswz1] = kp1;
  *(uint4*)&Vg[0][vrow * SKG + vswz0] = vp0;
  *(uint4*)&Vg[0][vrow * SKG + vswz1] = vp1;

  // ---- Q direct to registers: B-frag n = qcol*32+al, k(ci) = kst*16+h*8+j
  const int q_l = qcol * 32 + al;
  const float* qp = qg + t0 + q_l;
  float qv[4][8];
#pragma unroll
  for (int kst = 0; kst < 4; ++kst)
#pragma unroll
    for (int j = 0; j < 8; ++j)
      qv[kst][j] = qp[(size_t)(kst * 16 + h * 8 + j) * TLEN] * QSCALE;
  bf16x8 qfrag[4];
#pragma unroll
  for (int kst = 0; kst < 4; ++kst)
    qfrag[kst] = mk8(cvtpk(qv[kst][0], qv[kst][1]), cvtpk(qv[kst][2], qv[kst][3]),
                     cvtpk(qv[kst][4], qv[kst][5]), cvtpk(qv[kst][6], qv[kst][7]));

  __syncthreads();   // buf 0 staged (all groups)

  // per-lane swizzled read offsets
  int koff[4];   // K frag: row = al, chunk = (2kst+h) ^ (al&7)
#pragma unroll
  for (int kst = 0; kst < 4; ++kst) koff[kst] = ((2 * kst + h) ^ (al & 7)) * 8;
  const int vx = (al >> 1) & 3;
  int voff[2];   // V frag: row = mtc*32+al, chunk = (2kst+h) ^ ((row>>1)&3) = ^vx
#pragma unroll
  for (int kst = 0; kst < 2; ++kst) voff[kst] = ((2 * kst + h) ^ vx) * 8;

  f32x16 of0, of1;
#pragma unroll
  for (int i = 0; i < 16; ++i) { of0[i] = 0.f; of1[i] = 0.f; }
  float l_acc = 0.f;

  for (int it = 0; it < NITG; ++it) {
    const int cur = it & 1;

    // ---- issue next chunk's global loads first (overlap with compute)
    if (it + 1 < NITG) {
      const int s1 = kbase + (it + 1) * SKG;
      kp0 = *(const uint4*)(ktb + (size_t)(s1 + krow) * CD + (kcb + 0) * 8);
      kp1 = *(const uint4*)(ktb + (size_t)(s1 + krow) * CD + (kcb + 1) * 8);
      vp0 = *(const uint4*)(vnb + (size_t)vrow * STOT + s1 + (vcb + 0) * 8);
      vp1 = *(const uint4*)(vnb + (size_t)vrow * STOT + s1 + (vcb + 1) * 8);
    }

    const ushort* kt = Kg[cur];
    const ushort* vt = Vg[cur];

    // ---- S^T = K.Q^T : A=K rows (m=key=al), B=Q; D col=q(al),
    // row=key=(reg&3)+8*(reg>>2)+4h. p = exp2(s); fixed scale cancels in O/l.
    f32x16 acc;
#pragma unroll
    for (int i = 0; i < 16; ++i) acc[i] = 0.f;
#pragma unroll
    for (int kst = 0; kst < 4; ++kst) {
      bf16x8 afr = *(const bf16x8*)&kt[al * CD + koff[kst]];
      acc = __builtin_amdgcn_mfma_f32_32x32x16_bf16(afr, qfrag[kst], acc, 0, 0, 0);
    }
    uint ulo[4], uhi[4];   // packed bf16 P pairs, chunk rq covers keys 8rq+4h+0..3
#pragma unroll
    for (int rq = 0; rq < 4; ++rq) {
      float p0 = exp2f(acc[4 * rq + 0]);
      float p1 = exp2f(acc[4 * rq + 1]);
      float p2 = exp2f(acc[4 * rq + 2]);
      float p3 = exp2f(acc[4 * rq + 3]);
      l_acc += (p0 + p1) + (p2 + p3);
      ulo[rq] = cvtpk(p0, p1);
      uhi[rq] = cvtpk(p2, p3);
    }

    // ---- build PV B-frags in-register (chunk pair (2kst,2kst+1) + permlane)
    bf16x8 pfr[2];
#pragma unroll
    for (int kst = 0; kst < 2; ++kst) {
      uint xlo = ulo[2 * kst], ylo = ulo[2 * kst + 1];
      uint xhi = uhi[2 * kst], yhi = uhi[2 * kst + 1];
      plswap(xlo, ylo);
      plswap(xhi, yhi);
      pfr[kst] = mk8(xlo, xhi, ylo, yhi);
    }

    // ---- O^T += V.P^T : A=V rows (m=ci mtc*32+al)
#pragma unroll
    for (int kst = 0; kst < 2; ++kst) {
      bf16x8 v0 = *(const bf16x8*)&vt[(0 * 32 + al) * SKG + voff[kst]];
      bf16x8 v1 = *(const bf16x8*)&vt[(1 * 32 + al) * SKG + voff[kst]];
      of0 = __builtin_amdgcn_mfma_f32_32x32x16_bf16(v0, pfr[kst], of0, 0, 0, 0);
      of1 = __builtin_amdgcn_mfma_f32_32x32x16_bf16(v1, pfr[kst], of1, 0, 0, 0);
    }

    // ---- stage prefetched chunk; single barrier per iter
    if (it + 1 < NITG) {
      const int nb = cur ^ 1;
      *(uint4*)&Kg[nb][krow * CD + kswz0] = kp0;
      *(uint4*)&Kg[nb][krow * CD + kswz1] = kp1;
      *(uint4*)&Vg[nb][vrow * SKG + vswz0] = vp0;
      *(uint4*)&Vg[nb][vrow * SKG + vswz1] = vp1;
      __syncthreads();
    }
  }

  // ---- epilogue: merge 4 groups' partial O + l in LDS (arena reused) --------
  __syncthreads();   // all compute done; arena free
  float* fa = (float*)arena;
  float* tA = fa;                  // [64][68] f32 (padded rows, 16B aligned)
  float* tB = fa + 64 * 68;
  float* lf = fa + 2 * 64 * 68;    // [4][64]
  float lv = l_acc + __shfl_xor(l_acc, 32);
  if (h == 0) lf[grp * 64 + q_l] = lv;

  // of reg r -> ci = (r&3) + 8*(r>>2) + 4h : regs 4rq..4rq+3 = ci 8rq+4h+0..3
  if (grp >= 2) {
    float* T = (grp == 2) ? tA : tB;
#pragma unroll
    for (int rq = 0; rq < 4; ++rq) {
      *(f32x4*)&T[q_l * 68 + 8 * rq + 4 * h] =
          f32x4{of0[4 * rq + 0], of0[4 * rq + 1], of0[4 * rq + 2], of0[4 * rq + 3]};
      *(f32x4*)&T[q_l * 68 + 32 + 8 * rq + 4 * h] =
          f32x4{of1[4 * rq + 0], of1[4 * rq + 1], of1[4 * rq + 2], of1[4 * rq + 3]};
    }
  }
  __syncthreads();
  if (grp < 2) {
    const float* T = (grp == 0) ? tA : tB;
#pragma unroll
    for (int rq = 0; rq < 4; ++rq) {
      f32x4 a = *(const f32x4*)&T[q_l * 68 + 8 * rq + 4 * h];
      f32x4 c = *(const f32x4*)&T[q_l * 68 + 32 + 8 * rq + 4 * h];
#pragma unroll
      for (int j = 0; j < 4; ++j) { of0[4 * rq + j] += a[j]; of1[4 * rq + j] += c[j]; }
    }
  }
  __syncthreads();
  if (grp == 1) {
#pragma unroll
    for (int rq = 0; rq < 4; ++rq) {
      *(f32x4*)&tA[q_l * 68 + 8 * rq + 4 * h] =
          f32x4{of0[4 * rq + 0], of0[4 * rq + 1], of0[4 * rq + 2], of0[4 * rq + 3]};
      *(f32x4*)&tA[q_l * 68 + 32 + 8 * rq + 4 * h] =
          f32x4{of1[4 * rq + 0], of1[4 * rq + 1], of1[4 * rq + 2], of1[4 * rq + 3]};
    }
  }
  __syncthreads();
  if (grp == 0) {
#pragma unroll
    for (int rq = 0; rq < 4; ++rq) {
      f32x4 a = *(const f32x4*)&tA[q_l * 68 + 8 * rq + 4 * h];
      f32x4 c = *(const f32x4*)&tA[q_l * 68 + 32 + 8 * rq + 4 * h];
#pragma unroll
      for (int j = 0; j < 4; ++j) { of0[4 * rq + j] += a[j]; of1[4 * rq + j] += c[j]; }
    }
    float lsum = lf[q_l] + lf[64 + q_l] + lf[128 + q_l] + lf[192 + q_l];
    float inv = 1.0f / lsum;
    float* ob = og + t0 + q_l;
#pragma unroll
    for (int r = 0; r < 16; ++r) {
      int ci = (r & 3) + 8 * (r >> 2) + 4 * h;
      ob[(size_t)ci * TLEN] = of0[r] * inv;            // coalesced f32 across al
      ob[(size_t)(32 + ci) * TLEN] = of1[r] * inv;
    }
  }
}

extern "C" void kernel_launch(void* const* d_in, const int* in_sizes, int n_in,
                              void* d_out, int out_size, void* d_ws, size_t ws_size,
                              hipStream_t stream) {
  const float* x   = (const float*)d_in[0];   // (4, 1536, 1024) fp32
  const float* ekv = (const float*)d_in[1];   // (4, 1024, 1024) fp32
  float* out = (float*)d_out;                 // (4, 512, 1024) fp32
  // workspace: ktw 8MB | vnw 8MB
  ushort* ktw = (ushort*)d_ws;
  ushort* vnw = ktw + (size_t)32 * STOT * CD;
  repack_kernel<<<dim3(32, 32, 2), 256, 0, stream>>>(x, ekv, ktw, vnw);
  qkv_attn_ws<<<32 * 16, 512, 0, stream>>>(x, ktw, vnw, out);
}